// Round 1
// baseline (357.876 us; speedup 1.0000x reference)
//
#include <hip/hip_runtime.h>
#include <stdint.h>

#define NPROJ 256
#define DIM 128
#define MT 64                    // tokens per block
#define PCHUNK 32                // projections per LDS chunk
#define NCHUNK (NPROJ / PCHUNK)  // 8
#define LSTR 136                 // padded LDS row stride in bf16 elems (128+8 -> 272B, 16B aligned)
#define TAU 2.0e-3f              // refine threshold on |k_proj_fast|
#define QCAP 512
#define DEQ 0.004895758348888673f  // sqrt(pi/2)/256

typedef __attribute__((ext_vector_type(8))) short bf16x8;
typedef __attribute__((ext_vector_type(4))) float f32x4;

__device__ __forceinline__ ushort f2bf(float x) {
    union { float f; uint32_t u; } v; v.f = x;
    uint32_t r = v.u + 0x7FFFu + ((v.u >> 16) & 1u);   // RNE
    return (ushort)(r >> 16);
}
__device__ __forceinline__ float bf2f(ushort h) {
    union { float f; uint32_t u; } v; v.u = ((uint32_t)h) << 16;
    return v.f;
}

__global__ __launch_bounds__(256, 2) void qjl_main(
    const float* __restrict__ qg, const float* __restrict__ kg,
    const float* __restrict__ Sg, float* __restrict__ out)
{
    __shared__ ushort kh[MT * LSTR];
    __shared__ ushort kl[MT * LSTR];
    __shared__ ushort qh[MT * LSTR];
    __shared__ ushort sh[PCHUNK * LSTR];
    __shared__ ushort sl[PCHUNK * LSTR];
    __shared__ float  est_s[MT];
    __shared__ uint32_t qmeta[QCAP];
    __shared__ float    qdlt[QCAP];
    __shared__ int      qn;

    const int tid  = threadIdx.x;
    const int lane = tid & 63;
    const int wv   = tid >> 6;
    const long tok0 = (long)blockIdx.x * MT;

    if (tid == 0) qn = 0;

    // ---- stage K (hi+lo) and Q (hi) tiles: 64 x 128 fp32 -> bf16 planes ----
    {
        const float4* k4 = (const float4*)(kg + tok0 * DIM);
        const float4* q4 = (const float4*)(qg + tok0 * DIM);
        #pragma unroll
        for (int i = 0; i < 8; i++) {
            int f = tid + i * 256;            // 0..2047 float4 index
            int row = f >> 5, c4 = f & 31;
            int off = row * LSTR + c4 * 4;
            float4 kv = k4[f];
            ushort h0 = f2bf(kv.x), h1 = f2bf(kv.y), h2 = f2bf(kv.z), h3 = f2bf(kv.w);
            kh[off + 0] = h0; kh[off + 1] = h1; kh[off + 2] = h2; kh[off + 3] = h3;
            kl[off + 0] = f2bf(kv.x - bf2f(h0));
            kl[off + 1] = f2bf(kv.y - bf2f(h1));
            kl[off + 2] = f2bf(kv.z - bf2f(h2));
            kl[off + 3] = f2bf(kv.w - bf2f(h3));
            float4 qv = q4[f];
            qh[off + 0] = f2bf(qv.x); qh[off + 1] = f2bf(qv.y);
            qh[off + 2] = f2bf(qv.z); qh[off + 3] = f2bf(qv.w);
        }
    }

    float est[4] = {0.f, 0.f, 0.f, 0.f};
    const int arow = wv * 16 + (lane & 15);    // A-operand row (token within block)
    const int kq   = (lane >> 4) * 8;          // A/B k-offset within a 32-chunk
    const int brow = lane & 15;                // B-operand row (proj within tile)

    for (int c = 0; c < NCHUNK; c++) {
        if (c) __syncthreads();                // protect S chunk buffer reuse
        // ---- stage S chunk: 32 x 128 fp32 -> bf16 hi/lo ----
        {
            const float4* s4 = (const float4*)(Sg + (long)c * PCHUNK * DIM);
            #pragma unroll
            for (int i = 0; i < 4; i++) {
                int f = tid + i * 256;         // 0..1023
                int row = f >> 5, c4 = f & 31;
                int off = row * LSTR + c4 * 4;
                float4 sv = s4[f];
                ushort h0 = f2bf(sv.x), h1 = f2bf(sv.y), h2 = f2bf(sv.z), h3 = f2bf(sv.w);
                sh[off + 0] = h0; sh[off + 1] = h1; sh[off + 2] = h2; sh[off + 3] = h3;
                sl[off + 0] = f2bf(sv.x - bf2f(h0));
                sl[off + 1] = f2bf(sv.y - bf2f(h1));
                sl[off + 2] = f2bf(sv.z - bf2f(h2));
                sl[off + 3] = f2bf(sv.w - bf2f(h3));
            }
        }
        __syncthreads();

        f32x4 kacc0 = {0,0,0,0}, kacc1 = {0,0,0,0};
        f32x4 qacc0 = {0,0,0,0}, qacc1 = {0,0,0,0};
        #pragma unroll
        for (int ks = 0; ks < 4; ks++) {
            int acol = ks * 32 + kq;
            bf16x8 akh = *(const bf16x8*)&kh[arow * LSTR + acol];
            bf16x8 akl = *(const bf16x8*)&kl[arow * LSTR + acol];
            bf16x8 aqh = *(const bf16x8*)&qh[arow * LSTR + acol];
            bf16x8 b0h = *(const bf16x8*)&sh[brow * LSTR + acol];
            bf16x8 b0l = *(const bf16x8*)&sl[brow * LSTR + acol];
            bf16x8 b1h = *(const bf16x8*)&sh[(brow + 16) * LSTR + acol];
            bf16x8 b1l = *(const bf16x8*)&sl[(brow + 16) * LSTR + acol];
            kacc0 = __builtin_amdgcn_mfma_f32_16x16x32_bf16(akh, b0h, kacc0, 0, 0, 0);
            kacc0 = __builtin_amdgcn_mfma_f32_16x16x32_bf16(akl, b0h, kacc0, 0, 0, 0);
            kacc0 = __builtin_amdgcn_mfma_f32_16x16x32_bf16(akh, b0l, kacc0, 0, 0, 0);
            qacc0 = __builtin_amdgcn_mfma_f32_16x16x32_bf16(aqh, b0h, qacc0, 0, 0, 0);
            kacc1 = __builtin_amdgcn_mfma_f32_16x16x32_bf16(akh, b1h, kacc1, 0, 0, 0);
            kacc1 = __builtin_amdgcn_mfma_f32_16x16x32_bf16(akl, b1h, kacc1, 0, 0, 0);
            kacc1 = __builtin_amdgcn_mfma_f32_16x16x32_bf16(akh, b1l, kacc1, 0, 0, 0);
            qacc1 = __builtin_amdgcn_mfma_f32_16x16x32_bf16(aqh, b1h, qacc1, 0, 0, 0);
        }

        // ---- combine: est += q_proj * sign(k_proj); queue near-zero k_proj ----
        // C layout: col = lane&15 (proj), row = (lane>>4)*4 + r (token)
        #pragma unroll
        for (int r = 0; r < 4; r++) {
            int tl = wv * 16 + (lane >> 4) * 4 + r;
            float kv = kacc0[r], qv = qacc0[r];
            float s = (kv > 0.f) ? 1.f : -1.f;
            est[r] += qv * s;
            if (fabsf(kv) < TAU) {
                int p = c * PCHUNK + (lane & 15);
                int idx = atomicAdd(&qn, 1);
                if (idx < QCAP) {
                    qmeta[idx] = (uint32_t)tl | ((uint32_t)p << 8) | ((kv > 0.f ? 1u : 0u) << 16);
                    qdlt[idx]  = DEQ * qv * s;
                }
            }
            kv = kacc1[r]; qv = qacc1[r];
            s = (kv > 0.f) ? 1.f : -1.f;
            est[r] += qv * s;
            if (fabsf(kv) < TAU) {
                int p = c * PCHUNK + 16 + (lane & 15);
                int idx = atomicAdd(&qn, 1);
                if (idx < QCAP) {
                    qmeta[idx] = (uint32_t)tl | ((uint32_t)p << 8) | ((kv > 0.f ? 1u : 0u) << 16);
                    qdlt[idx]  = DEQ * qv * s;
                }
            }
        }
    }

    // ---- reduce over the 16 proj-columns held across lanes (low 4 lane bits) ----
    #pragma unroll
    for (int r = 0; r < 4; r++) {
        float e = est[r];
        e += __shfl_xor(e, 1);
        e += __shfl_xor(e, 2);
        e += __shfl_xor(e, 4);
        e += __shfl_xor(e, 8);
        if ((lane & 15) == 0) est_s[wv * 16 + (lane >> 4) * 4 + r] = DEQ * e;
    }
    __syncthreads();

    // ---- refine: exact fp64 dot for near-zero k_proj candidates ----
    int nc = qn < QCAP ? qn : QCAP;
    for (int i = wv; i < nc; i += 4) {
        uint32_t m = qmeta[i];
        int tl = m & 255;
        int p  = (m >> 8) & 255;
        int sf = (m >> 16) & 1;
        const float2* kr = (const float2*)(kg + (tok0 + tl) * DIM);
        const float2* sr = (const float2*)(Sg + (long)p * DIM);
        float2 ka = kr[lane], sa = sr[lane];
        double acc = (double)ka.x * (double)sa.x + (double)ka.y * (double)sa.y;
        acc += __shfl_xor(acc, 1);
        acc += __shfl_xor(acc, 2);
        acc += __shfl_xor(acc, 4);
        acc += __shfl_xor(acc, 8);
        acc += __shfl_xor(acc, 16);
        acc += __shfl_xor(acc, 32);
        int st = (acc > 0.0) ? 1 : 0;
        if (lane == 0 && st != sf) atomicAdd(&est_s[tl], -2.f * qdlt[i]);
    }
    __syncthreads();

    if (tid < MT) out[tok0 + tid] = est_s[tid];
}

extern "C" void kernel_launch(void* const* d_in, const int* in_sizes, int n_in,
                              void* d_out, int out_size, void* d_ws, size_t ws_size,
                              hipStream_t stream) {
    const float* q = (const float*)d_in[0];
    const float* k = (const float*)d_in[1];
    const float* S = (const float*)d_in[2];
    float* out = (float*)d_out;
    int nblocks = out_size / MT;   // 262144 / 64 = 4096
    hipLaunchKernelGGL(qjl_main, dim3(nblocks), dim3(256), 0, stream, q, k, S, out);
}

// Round 2
// 346.503 us; speedup vs baseline: 1.0328x; 1.0328x over previous
//
#include <hip/hip_runtime.h>
#include <stdint.h>

#define DIM 128
#define NPROJ 256
#define TPB 128                    // tokens per block (4 waves x 32)
#define TAU 0.035f                 // refine threshold on |k_proj_f16|
#define QCAP 512
#define DEQ 0.004895758348888673f  // sqrt(pi/2)/256

typedef _Float16 f16x8 __attribute__((ext_vector_type(8)));
typedef float f32x4 __attribute__((ext_vector_type(4)));

// ---- prep: S fp32 -> f16 B-fragments, pre-swizzled into MFMA lane order ----
// frag id fid = (c*4 + ks)*2 + f   (c: 32-proj chunk, ks: k-step, f: 16-proj tile)
// lane l holds B[n=p][k=d] els: p = c*32 + f*16 + (l&15), d = ks*32 + (l>>4)*8 + j
__global__ __launch_bounds__(256) void qjl_prep(const float* __restrict__ Sg,
                                                _Float16* __restrict__ ws) {
    int t = blockIdx.x * 256 + threadIdx.x;   // 0..4095
    int lane = t & 63, fid = t >> 6;          // 64 frags
    int f = fid & 1, ks = (fid >> 1) & 3, c = fid >> 3;
    int p = c * 32 + f * 16 + (lane & 15);
    int d0 = ks * 32 + (lane >> 4) * 8;
    const float4* s4 = (const float4*)(Sg + p * DIM + d0);
    float4 a = s4[0], b = s4[1];
    f16x8 h = {(_Float16)a.x, (_Float16)a.y, (_Float16)a.z, (_Float16)a.w,
               (_Float16)b.x, (_Float16)b.y, (_Float16)b.z, (_Float16)b.w};
    *(f16x8*)(ws + (size_t)fid * 512 + lane * 8) = h;
}

__global__ __launch_bounds__(256, 3) void qjl_main(
    const float* __restrict__ qg, const float* __restrict__ kg,
    const float* __restrict__ Sg, const _Float16* __restrict__ ws,
    float* __restrict__ out)
{
    __shared__ float    est_s[TPB];
    __shared__ uint32_t qmeta[QCAP];
    __shared__ float    qdlt[QCAP];
    __shared__ int      qn;

    const int tid = threadIdx.x, lane = tid & 63, wv = tid >> 6;
    const int m = lane & 15, quad = lane >> 4;
    const long tok0 = (long)blockIdx.x * TPB;
    if (tid == 0) qn = 0;
    __syncthreads();

    // ---- A fragments: fp32 -> f16 straight into registers (no LDS) ----
    f16x8 ak[2][4], aq[2][4];
    #pragma unroll
    for (int rb = 0; rb < 2; ++rb) {
        long row = tok0 + wv * 32 + rb * 16 + m;
        const float* kr = kg + row * DIM;
        const float* qr = qg + row * DIM;
        #pragma unroll
        for (int ks = 0; ks < 4; ++ks) {
            int d0 = ks * 32 + quad * 8;
            float4 x = *(const float4*)(kr + d0);
            float4 y = *(const float4*)(kr + d0 + 4);
            ak[rb][ks] = (f16x8){(_Float16)x.x, (_Float16)x.y, (_Float16)x.z, (_Float16)x.w,
                                 (_Float16)y.x, (_Float16)y.y, (_Float16)y.z, (_Float16)y.w};
            float4 u = *(const float4*)(qr + d0);
            float4 v = *(const float4*)(qr + d0 + 4);
            aq[rb][ks] = (f16x8){(_Float16)u.x, (_Float16)u.y, (_Float16)u.z, (_Float16)u.w,
                                 (_Float16)v.x, (_Float16)v.y, (_Float16)v.z, (_Float16)v.w};
        }
    }

    float est[8] = {0.f, 0.f, 0.f, 0.f, 0.f, 0.f, 0.f, 0.f};

    // ---- barrier-free main loop over 8 proj-chunks ----
    for (int c = 0; c < 8; ++c) {
        f16x8 b0[4], b1[4];
        #pragma unroll
        for (int ks = 0; ks < 4; ++ks) {
            b0[ks] = *(const f16x8*)(ws + (size_t)(c * 8 + ks * 2 + 0) * 512 + lane * 8);
            b1[ks] = *(const f16x8*)(ws + (size_t)(c * 8 + ks * 2 + 1) * 512 + lane * 8);
        }
        #pragma unroll
        for (int rb = 0; rb < 2; ++rb) {
            f32x4 kacc0 = {0,0,0,0}, kacc1 = {0,0,0,0};
            f32x4 qacc0 = {0,0,0,0}, qacc1 = {0,0,0,0};
            #pragma unroll
            for (int ks = 0; ks < 4; ++ks) {
                kacc0 = __builtin_amdgcn_mfma_f32_16x16x32_f16(ak[rb][ks], b0[ks], kacc0, 0, 0, 0);
                kacc1 = __builtin_amdgcn_mfma_f32_16x16x32_f16(ak[rb][ks], b1[ks], kacc1, 0, 0, 0);
                qacc0 = __builtin_amdgcn_mfma_f32_16x16x32_f16(aq[rb][ks], b0[ks], qacc0, 0, 0, 0);
                qacc1 = __builtin_amdgcn_mfma_f32_16x16x32_f16(aq[rb][ks], b1[ks], qacc1, 0, 0, 0);
            }
            // C layout: col = lane&15 (proj in tile), row = quad*4 + r (token in 16-block)
            #pragma unroll
            for (int r = 0; r < 4; ++r) {
                int tl = wv * 32 + rb * 16 + quad * 4 + r;
                {
                    float kv = kacc0[r], qv = qacc0[r];
                    float sg = (kv > 0.f) ? 1.f : -1.f;
                    est[rb * 4 + r] += qv * sg;
                    if (fabsf(kv) < TAU) {
                        int p = c * 32 + m;
                        int idx = atomicAdd(&qn, 1);
                        if (idx < QCAP) {
                            qmeta[idx] = (uint32_t)tl | ((uint32_t)p << 8) | ((kv > 0.f ? 1u : 0u) << 16);
                            qdlt[idx]  = DEQ * qv * sg;
                        }
                    }
                }
                {
                    float kv = kacc1[r], qv = qacc1[r];
                    float sg = (kv > 0.f) ? 1.f : -1.f;
                    est[rb * 4 + r] += qv * sg;
                    if (fabsf(kv) < TAU) {
                        int p = c * 32 + 16 + m;
                        int idx = atomicAdd(&qn, 1);
                        if (idx < QCAP) {
                            qmeta[idx] = (uint32_t)tl | ((uint32_t)p << 8) | ((kv > 0.f ? 1u : 0u) << 16);
                            qdlt[idx]  = DEQ * qv * sg;
                        }
                    }
                }
            }
        }
    }

    // ---- reduce est over the 16 proj-lanes ----
    #pragma unroll
    for (int rb = 0; rb < 2; ++rb) {
        #pragma unroll
        for (int r = 0; r < 4; ++r) {
            float e = est[rb * 4 + r];
            e += __shfl_xor(e, 1);
            e += __shfl_xor(e, 2);
            e += __shfl_xor(e, 4);
            e += __shfl_xor(e, 8);
            if (m == 0) est_s[wv * 32 + rb * 16 + quad * 4 + r] = DEQ * e;
        }
    }
    __syncthreads();

    // ---- refine: exact fp64 dot for near-zero k_proj candidates ----
    int nc = qn < QCAP ? qn : QCAP;
    for (int i = wv; i < nc; i += 4) {
        uint32_t mm = qmeta[i];
        int tl = mm & 255;
        int p  = (mm >> 8) & 255;
        int sf = (mm >> 16) & 1;
        const float2* kr = (const float2*)(kg + (tok0 + tl) * DIM);
        const float2* sr = (const float2*)(Sg + (long)p * DIM);
        float2 ka = kr[lane], sa = sr[lane];
        double acc = (double)ka.x * (double)sa.x + (double)ka.y * (double)sa.y;
        acc += __shfl_xor(acc, 1);
        acc += __shfl_xor(acc, 2);
        acc += __shfl_xor(acc, 4);
        acc += __shfl_xor(acc, 8);
        acc += __shfl_xor(acc, 16);
        acc += __shfl_xor(acc, 32);
        int st = (acc > 0.0) ? 1 : 0;
        if (lane == 0 && st != sf) atomicAdd(&est_s[tl], -2.f * qdlt[i]);
    }
    __syncthreads();

    if (tid < TPB) out[tok0 + tid] = est_s[tid];
}

extern "C" void kernel_launch(void* const* d_in, const int* in_sizes, int n_in,
                              void* d_out, int out_size, void* d_ws, size_t ws_size,
                              hipStream_t stream) {
    const float* q = (const float*)d_in[0];
    const float* k = (const float*)d_in[1];
    const float* S = (const float*)d_in[2];
    float* out = (float*)d_out;
    _Float16* ws = (_Float16*)d_ws;
    hipLaunchKernelGGL(qjl_prep, dim3(16), dim3(256), 0, stream, S, ws);
    int nblocks = out_size / TPB;   // 262144 / 128 = 2048
    hipLaunchKernelGGL(qjl_main, dim3(nblocks), dim3(256), 0, stream, q, k, S, ws, out);
}